// Round 2
// baseline (1202.257 us; speedup 1.0000x reference)
//
#include <hip/hip_runtime.h>
#include <hip/hip_bf16.h>

// MoE gate: logits = x(T,4096) @ W(64,4096)^T ; softmax ; group-limited top-k.
// T = 16384, E = 64, H = 4096, groups = 8x8, topk_group = 3, top_k = 6.
// Outputs concatenated in d_out (float32): idx[T*6] (float-encoded ints),
// weight[T*6], sorted descending with jax top_k tie-breaking.
//
// Round-2 structure: x tile (32 x 128) staged in LDS (the 268 MB stream);
// W (1 MB, L2-resident) read straight from global as float4 — removes 4 of 6
// ds_read_b128 per inner step, making the loop VALU-bound (32 FMA / 2 LDS).

#define TM     32    // tokens per block
#define HK     128   // K-chunk staged in LDS
#define PITCH  132   // LDS row pitch in floats (pad 4 -> max 2-way aliasing, free)
#define NE     64
#define NH     4096
#define NTOPK  6

__global__ __launch_bounds__(256, 2) void moe_gate_kernel(
    const float* __restrict__ x, const float* __restrict__ w,
    float* __restrict__ out_idx, float* __restrict__ out_w)
{
    __shared__ float xs[TM * PITCH];   // 16.9 KB (reused as logits buffer)

    const int tid = threadIdx.x;
    const int tx  = tid & 15;          // expert-dim coord: experts tx+16j
    const int ty  = tid >> 4;          // token-dim coord: tokens ty, ty+16
    const int t0  = blockIdx.x * TM;

    float acc[2][4];
    #pragma unroll
    for (int i = 0; i < 2; ++i)
        #pragma unroll
        for (int j = 0; j < 4; ++j) acc[i][j] = 0.f;

    const int c4 = (tid & 31) << 2;    // float4 column within chunk: 0..124
    const int r0 = tid >> 5;           // staging row base: 0..7

    // Per-thread W row pointers (experts tx, tx+16, tx+32, tx+48).
    const float* wp0 = w + (size_t)tx * NH;
    const float* wp1 = wp0 + (size_t)16 * NH;
    const float* wp2 = wp0 + (size_t)32 * NH;
    const float* wp3 = wp0 + (size_t)48 * NH;

    for (int k0 = 0; k0 < NH; k0 += HK) {
        // ---- stage x tile (TM x HK), coalesced 512B per 32 lanes ----
        #pragma unroll
        for (int p = 0; p < 4; ++p) {
            const int r = r0 + (p << 3);
            const float4 v = *reinterpret_cast<const float4*>(
                x + (size_t)(t0 + r) * NH + k0 + c4);
            *reinterpret_cast<float4*>(&xs[r * PITCH + c4]) = v;
        }
        __syncthreads();

        // ---- inner: 2 tok x 4 exp; x from LDS, W from global (L2-hit) ----
        #pragma unroll 8
        for (int kk = 0; kk < HK; kk += 4) {
            const float4 xa = *reinterpret_cast<const float4*>(&xs[ty * PITCH + kk]);
            const float4 xb = *reinterpret_cast<const float4*>(&xs[(ty + 16) * PITCH + kk]);
            float4 wv[4];
            wv[0] = *reinterpret_cast<const float4*>(wp0 + k0 + kk);
            wv[1] = *reinterpret_cast<const float4*>(wp1 + k0 + kk);
            wv[2] = *reinterpret_cast<const float4*>(wp2 + k0 + kk);
            wv[3] = *reinterpret_cast<const float4*>(wp3 + k0 + kk);
            #pragma unroll
            for (int j = 0; j < 4; ++j) {
                acc[0][j] = fmaf(xa.x, wv[j].x, acc[0][j]);
                acc[0][j] = fmaf(xa.y, wv[j].y, acc[0][j]);
                acc[0][j] = fmaf(xa.z, wv[j].z, acc[0][j]);
                acc[0][j] = fmaf(xa.w, wv[j].w, acc[0][j]);
                acc[1][j] = fmaf(xb.x, wv[j].x, acc[1][j]);
                acc[1][j] = fmaf(xb.y, wv[j].y, acc[1][j]);
                acc[1][j] = fmaf(xb.z, wv[j].z, acc[1][j]);
                acc[1][j] = fmaf(xb.w, wv[j].w, acc[1][j]);
            }
        }
        __syncthreads();
    }

    // ---- epilogue: logits -> LDS (reuse xs), then fused gating ----
    float* lg = xs;                    // 32 tokens x 64 experts, pitch 66
    #pragma unroll
    for (int i = 0; i < 2; ++i)
        #pragma unroll
        for (int j = 0; j < 4; ++j)
            lg[(ty + (i << 4)) * 66 + (tx + (j << 4))] = acc[i][j];
    __syncthreads();

    const int lane = tid & 63;         // lane == expert index
    const int wid  = tid >> 6;         // wave 0..3, each handles 8 tokens
    for (int tt = wid * 8; tt < wid * 8 + 8; ++tt) {
        const float logit = lg[tt * 66 + lane];

        // softmax over 64 experts (wave-wide)
        float m = logit;
        #pragma unroll
        for (int s = 32; s > 0; s >>= 1) m = fmaxf(m, __shfl_xor(m, s));
        const float ex = expf(logit - m);
        float sum = ex;
        #pragma unroll
        for (int s = 32; s > 0; s >>= 1) sum += __shfl_xor(sum, s);
        const float score = ex / sum;

        // per-group max (groups of 8 consecutive experts)
        float gm = score;
        #pragma unroll
        for (int s = 4; s > 0; s >>= 1) gm = fmaxf(gm, __shfl_xor(gm, s));
        const int g = lane >> 3;

        // rank of this lane's group among the 8 group-maxima (stable, desc)
        int grank = 0;
        #pragma unroll
        for (int gg = 0; gg < 8; ++gg) {
            const float o = __shfl(gm, gg << 3);
            grank += (o > gm) || (o == gm && gg < g);
        }
        const float masked = (grank < 3) ? score : 0.0f;

        // rank among all 64 masked scores (stable, desc) == output position
        int rank = 0;
        for (int ee = 0; ee < 64; ++ee) {
            const float o = __shfl(masked, ee);
            rank += (o > masked) || (o == masked && ee < lane);
        }
        if (rank < NTOPK) {
            const int t = t0 + tt;
            out_idx[t * NTOPK + rank] = (float)lane;   // float-encoded index
            out_w[t * NTOPK + rank]   = masked;
        }
    }
}

extern "C" void kernel_launch(void* const* d_in, const int* in_sizes, int n_in,
                              void* d_out, int out_size, void* d_ws, size_t ws_size,
                              hipStream_t stream) {
    const float* x = (const float*)d_in[0];
    const float* w = (const float*)d_in[1];
    const int T = in_sizes[0] / NH;            // 16384 tokens
    float* outf    = (float*)d_out;
    float* out_idx = outf;                     // first T*6: indices
    float* out_w   = outf + (size_t)T * NTOPK; // then  T*6: weights

    dim3 grid(T / TM), block(256);
    hipLaunchKernelGGL(moe_gate_kernel, grid, block, 0, stream,
                       x, w, out_idx, out_w);
}

// Round 3
// 447.413 us; speedup vs baseline: 2.6871x; 2.6871x over previous
//
#include <hip/hip_runtime.h>
#include <hip/hip_bf16.h>

// MoE gate: logits = x(T,4096) @ W(64,4096)^T ; softmax ; group-limited top-k.
// T = 16384, E = 64, H = 4096, groups = 8x8, topk_group = 3, top_k = 6.
// Outputs concatenated in d_out (float32): idx[T*6] (float-encoded ints),
// weight[T*6], sorted descending with jax top_k tie-breaking.
//
// Round-3: split-K(2) GEMM -> partial logits in d_ws, then a small gate kernel.
// GEMM: TM=64 tokens/block, all 64 experts, 4x4 thread tile, x & W tiles in
// LDS (pitch 132), inner loop = 8 ds_read_b128 (all base+imm) + 64 FMA.
// grid 512 = 2 blocks/CU so paired blocks hide each other's staging barriers.

#define TM     64    // tokens per block
#define HK     128   // K-chunk staged in LDS
#define PITCH  132   // LDS row pitch in floats (pad 4: x reads conflict-free, w 2-way)
#define NE     64
#define NH     4096
#define KSPLIT 2
#define KHALF  (NH / KSPLIT)   // 2048
#define NTOPK  6

__global__ __launch_bounds__(256, 2) void moe_gemm_kernel(
    const float* __restrict__ x, const float* __restrict__ w,
    float* __restrict__ partial, int T)
{
    __shared__ float xs[TM * PITCH];   // 33.8 KB
    __shared__ float ws[NE * PITCH];   // 33.8 KB

    const int tid  = threadIdx.x;
    const int tx   = tid & 15;         // expert coord: e = tx + 16j
    const int ty   = tid >> 4;         // token coord:  t = ty + 16i
    const int blk  = blockIdx.x;
    const int t0   = (blk >> 1) * TM;  // token block
    const int kb   = (blk & 1) * KHALF;// K half

    float acc[4][4];
    #pragma unroll
    for (int i = 0; i < 4; ++i)
        #pragma unroll
        for (int j = 0; j < 4; ++j) acc[i][j] = 0.f;

    const int c4 = (tid & 31) << 2;    // float4 column within chunk: 0..124
    const int r0 = tid >> 5;           // staging row base: 0..7

    const float* xrow = xs + ty * PITCH;
    const float* wrow = ws + tx * PITCH;

    for (int k0 = 0; k0 < KHALF; k0 += HK) {
        // ---- stage x tile (64 x 128) ----
        #pragma unroll
        for (int p = 0; p < 8; ++p) {
            const int r = r0 + (p << 3);
            const float4 v = *reinterpret_cast<const float4*>(
                x + (size_t)(t0 + r) * NH + kb + k0 + c4);
            *reinterpret_cast<float4*>(&xs[r * PITCH + c4]) = v;
        }
        // ---- stage W tile (64 x 128) ----
        #pragma unroll
        for (int p = 0; p < 8; ++p) {
            const int r = r0 + (p << 3);
            const float4 v = *reinterpret_cast<const float4*>(
                w + (size_t)r * NH + kb + k0 + c4);
            *reinterpret_cast<float4*>(&ws[r * PITCH + c4]) = v;
        }
        __syncthreads();

        // ---- inner: 4 tok x 4 exp, all LDS addresses base+imm ----
        #pragma unroll 8
        for (int kk = 0; kk < HK; kk += 4) {
            float4 xa[4], wv[4];
            xa[0] = *reinterpret_cast<const float4*>(xrow + kk);
            xa[1] = *reinterpret_cast<const float4*>(xrow + 16 * PITCH + kk);
            xa[2] = *reinterpret_cast<const float4*>(xrow + 32 * PITCH + kk);
            xa[3] = *reinterpret_cast<const float4*>(xrow + 48 * PITCH + kk);
            wv[0] = *reinterpret_cast<const float4*>(wrow + kk);
            wv[1] = *reinterpret_cast<const float4*>(wrow + 16 * PITCH + kk);
            wv[2] = *reinterpret_cast<const float4*>(wrow + 32 * PITCH + kk);
            wv[3] = *reinterpret_cast<const float4*>(wrow + 48 * PITCH + kk);
            #pragma unroll
            for (int i = 0; i < 4; ++i)
                #pragma unroll
                for (int j = 0; j < 4; ++j) {
                    acc[i][j] = fmaf(xa[i].x, wv[j].x, acc[i][j]);
                    acc[i][j] = fmaf(xa[i].y, wv[j].y, acc[i][j]);
                    acc[i][j] = fmaf(xa[i].z, wv[j].z, acc[i][j]);
                    acc[i][j] = fmaf(xa[i].w, wv[j].w, acc[i][j]);
                }
        }
        __syncthreads();
    }

    // ---- write partial logits: partial[half][t][e] ----
    float* pbase = partial + (size_t)(blk & 1) * T * NE;
    #pragma unroll
    for (int i = 0; i < 4; ++i)
        #pragma unroll
        for (int j = 0; j < 4; ++j)
            pbase[(size_t)(t0 + ty + (i << 4)) * NE + tx + (j << 4)] = acc[i][j];
}

__global__ __launch_bounds__(256, 4) void moe_gate_kernel(
    const float* __restrict__ partial,
    float* __restrict__ out_idx, float* __restrict__ out_w, int T)
{
    const int tid  = threadIdx.x;
    const int lane = tid & 63;         // lane == expert index
    const int wid  = tid >> 6;         // wave 0..3, 8 tokens each
    const int tb   = blockIdx.x * 32 + wid * 8;

    for (int tt = 0; tt < 8; ++tt) {
        const int t = tb + tt;
        const float logit = partial[(size_t)t * NE + lane]
                          + partial[(size_t)(T + t) * NE + lane];

        // softmax over 64 experts (wave-wide)
        float m = logit;
        #pragma unroll
        for (int s = 32; s > 0; s >>= 1) m = fmaxf(m, __shfl_xor(m, s));
        const float ex = expf(logit - m);
        float sum = ex;
        #pragma unroll
        for (int s = 32; s > 0; s >>= 1) sum += __shfl_xor(sum, s);
        const float score = ex / sum;

        // per-group max (groups of 8 consecutive experts)
        float gm = score;
        #pragma unroll
        for (int s = 4; s > 0; s >>= 1) gm = fmaxf(gm, __shfl_xor(gm, s));
        const int g = lane >> 3;

        // rank of this lane's group among the 8 group-maxima (stable, desc)
        int grank = 0;
        #pragma unroll
        for (int gg = 0; gg < 8; ++gg) {
            const float o = __shfl(gm, gg << 3);
            grank += (o > gm) || (o == gm && gg < g);
        }
        const float masked = (grank < 3) ? score : 0.0f;

        // rank among all 64 masked scores (stable, desc) == output position
        int rank = 0;
        for (int ee = 0; ee < 64; ++ee) {
            const float o = __shfl(masked, ee);
            rank += (o > masked) || (o == masked && ee < lane);
        }
        if (rank < NTOPK) {
            out_idx[t * NTOPK + rank] = (float)lane;   // float-encoded index
            out_w[t * NTOPK + rank]   = masked;
        }
    }
}

extern "C" void kernel_launch(void* const* d_in, const int* in_sizes, int n_in,
                              void* d_out, int out_size, void* d_ws, size_t ws_size,
                              hipStream_t stream) {
    const float* x = (const float*)d_in[0];
    const float* w = (const float*)d_in[1];
    const int T = in_sizes[0] / NH;            // 16384 tokens
    float* outf    = (float*)d_out;
    float* out_idx = outf;                     // first T*6: indices
    float* out_w   = outf + (size_t)T * NTOPK; // then  T*6: weights
    float* partial = (float*)d_ws;             // KSPLIT * T * 64 floats = 8 MB

    dim3 gg((T / TM) * KSPLIT), gb(256);       // 512 blocks
    hipLaunchKernelGGL(moe_gemm_kernel, gg, gb, 0, stream, x, w, partial, T);

    dim3 hg(T / 32), hb(256);                  // 512 blocks
    hipLaunchKernelGGL(moe_gate_kernel, hg, hb, 0, stream,
                       partial, out_idx, out_w, T);
}